// Round 1
// baseline (296.620 us; speedup 1.0000x reference)
//
#include <hip/hip_runtime.h>
#include <math.h>

namespace {

constexpr int Hh = 384;
constexpr int Ww = 384;
constexpr int Bb = 4;
constexpr int HW = Hh * Ww;          // 147456
constexpr int NPIX = Bb * HW;        // 589824
constexpr int ITERS = 20;
constexpr int TPB = 256;
constexpr int NBLK = (NPIX + TPB - 1) / TPB;   // 2304

__device__ __forceinline__ float fsub_rn_(float a, float b) {
    return __fadd_rn(a, -b);   // exact same rounding as a-b, no contraction
}

// 9 pairwise weights for pixel (h,w) of batch-slice fmb = feature_map[b] ([3,HW])
__device__ __forceinline__ void compute_weights(const float* __restrict__ fmb,
                                                int h, int w, int hw,
                                                float* __restrict__ wgt) {
    float c0 = __fadd_rn(fmb[0 * HW + hw], 10.0f);
    float c1 = __fadd_rn(fmb[1 * HW + hw], 10.0f);
    float c2 = __fadd_rn(fmb[2 * HW + hw], 10.0f);
#pragma unroll
    for (int ki = 0; ki < 3; ++ki) {
#pragma unroll
        for (int kj = 0; kj < 3; ++kj) {
            const int k = ki * 3 + kj;
            const int hh = h + ki - 1;
            const int ww2 = w + kj - 1;
            if (hh < 0 || hh >= Hh || ww2 < 0 || ww2 >= Ww) {
                // padded tap: never used with nonzero u (u is zero-padded too)
                wgt[k] = 0.0f;
            } else {
                const int nhw = hh * Ww + ww2;
                float d0 = fsub_rn_(__fadd_rn(fmb[0 * HW + nhw], 10.0f), c0);
                float d1 = fsub_rn_(__fadd_rn(fmb[1 * HW + nhw], 10.0f), c1);
                float d2 = fsub_rn_(__fadd_rn(fmb[2 * HW + nhw], 10.0f), c2);
                float ss = __fadd_rn(__fadd_rn(__fmul_rn(d0, d0), __fmul_rn(d1, d1)),
                                     __fmul_rn(d2, d2));
                float color = __fdiv_rn(-ss, 0.5f);                 // /(2*0.5^2)
                const float spk = __fdiv_rn(
                    (float)((ki - 1) * (ki - 1) + (kj - 1) * (kj - 1)), 1800.0f);
                wgt[k] = __fmul_rn(3.0f, expf(fsub_rn_(color, spk)));
            }
        }
    }
}

// state byte: bit0 = (channel0 == 0.55f), bit1 = (channel1 == 0.55f)
__global__ __launch_bounds__(TPB) void precomp_store(
        const float* __restrict__ fm, const float* __restrict__ x,
        const float* __restrict__ t, float* __restrict__ kern,
        unsigned char* __restrict__ st) {
    int idx = blockIdx.x * TPB + threadIdx.x;
    if (idx >= NPIX) return;
    int b = idx / HW, hw = idx - b * HW;
    int h = hw / Ww, w = hw - h * Ww;
    float wgt[9];
    compute_weights(fm + (size_t)b * 3 * HW, h, w, hw, wgt);
#pragma unroll
    for (int k = 0; k < 9; ++k)
        kern[((size_t)b * 9 + k) * HW + hw] = wgt[k];
    float xm = __fmul_rn(x[idx], t[idx]);
    st[idx] = (xm > 0.5f) ? (unsigned char)2 : (unsigned char)1;
}

__global__ __launch_bounds__(TPB) void init_state_only(
        const float* __restrict__ x, const float* __restrict__ t,
        unsigned char* __restrict__ st) {
    int idx = blockIdx.x * TPB + threadIdx.x;
    if (idx >= NPIX) return;
    float xm = __fmul_rn(x[idx], t[idx]);
    st[idx] = (xm > 0.5f) ? (unsigned char)2 : (unsigned char)1;
}

template <bool PRE>
__global__ __launch_bounds__(TPB) void iter_kernel(
        const unsigned char* __restrict__ sin_,
        unsigned char* __restrict__ sout,
        const float* __restrict__ kern,   // used if PRE
        const float* __restrict__ fm,     // used if !PRE
        const float* __restrict__ t) {
    int idx = blockIdx.x * TPB + threadIdx.x;
    if (idx >= NPIX) return;
    int b = idx / HW, hw = idx - b * HW;
    int h = hw / Ww, w = hw - h * Ww;

    // -log of the two possible r values (exact f32 inputs, true-rounded result)
    const float Lg45 = (float)(-log((double)0.45f));
    const float Lg55 = (float)(-log((double)0.55f));

    float wgt[9];
    if (PRE) {
#pragma unroll
        for (int k = 0; k < 9; ++k)
            wgt[k] = kern[((size_t)b * 9 + k) * HW + hw];
    } else {
        compute_weights(fm + (size_t)b * 3 * HW, h, w, hw, wgt);
    }

    const unsigned char* sb = sin_ + (size_t)b * HW;
    float a0 = 0.0f, a1 = 0.0f;
#pragma unroll
    for (int ki = 0; ki < 3; ++ki) {
#pragma unroll
        for (int kj = 0; kj < 3; ++kj) {
            const int k = ki * 3 + kj;
            const int hh = h + ki - 1;
            const int ww2 = w + kj - 1;
            if (hh >= 0 && hh < Hh && ww2 >= 0 && ww2 < Ww) {
                unsigned char s = sb[hh * Ww + ww2];
                float u0 = (s & 1) ? Lg55 : Lg45;
                float u1 = (s & 2) ? Lg55 : Lg45;
                a0 = __fadd_rn(a0, __fmul_rn(u0, wgt[k]));
                a1 = __fadd_rn(a1, __fmul_rn(u1, wgt[k]));
            }
            // OOB: reference adds exactly +0.0 -> no-op
        }
    }
    float f0 = expf(-a0);
    float f1 = __fmul_rn(expf(-a1), t[idx]);
    f0 = __fadd_rn(f0, 1e-6f);
    f1 = __fadd_rn(f1, 1e-6f);
    float S = __fadd_rn(f0, f1);
    float f0n = __fdiv_rn(f0, S);
    float f1n = __fdiv_rn(f1, S);
    unsigned char ns = (unsigned char)((f0n > 0.5f ? 1 : 0) | (f1n > 0.5f ? 2 : 0));
    sout[idx] = ns;
}

__global__ __launch_bounds__(TPB) void finalize_kernel(
        const unsigned char* __restrict__ st, float* __restrict__ out,
        int* __restrict__ counts) {
    int idx = blockIdx.x * TPB + threadIdx.x;
    if (idx >= NPIX) return;
    int b = idx / HW;                 // HW % 64 == 0 -> a wave never crosses b
    int bit = (st[idx] >> 1) & 1;
    out[idx] = (float)bit;
    unsigned long long m = __ballot(bit != 0);
    if ((threadIdx.x & 63) == 0)
        atomicAdd(&counts[b], (int)__popcll(m));
}

__global__ void write_valid(const int* __restrict__ counts,
                            float* __restrict__ out_valid) {
    int b = threadIdx.x;
    if (b < Bb) {
        float cf = (float)counts[b];
        const float lo = (float)(147456.0 * 0.05);   // f64 -> f32, same as JAX
        const float hi = (float)(147456.0 * 0.95);
        out_valid[b] = (cf >= lo && cf <= hi) ? 1.0f : 0.0f;
    }
}

}  // namespace

extern "C" void kernel_launch(void* const* d_in, const int* in_sizes, int n_in,
                              void* d_out, int out_size, void* d_ws, size_t ws_size,
                              hipStream_t stream) {
    const float* x  = (const float*)d_in[0];
    const float* tg = (const float*)d_in[1];
    const float* fm = (const float*)d_in[2];
    float* out = (float*)d_out;

    const size_t kernBytes = (size_t)Bb * 9 * HW * sizeof(float);  // ~21.2 MB
    const size_t stBytes   = (size_t)NPIX;                         // 589824

    char* ws = (char*)d_ws;
    // layout: [counts 256B][st0][st1][kern?]
    int* counts = (int*)ws;
    unsigned char* st0 = (unsigned char*)(ws + 256);
    unsigned char* st1 = st0 + stBytes;
    float* kern = (float*)(ws + 256 + 2 * stBytes);
    const bool pre = ws_size >= 256 + 2 * stBytes + kernBytes;

    hipMemsetAsync(counts, 0, 4 * sizeof(int), stream);

    if (pre) {
        precomp_store<<<NBLK, TPB, 0, stream>>>(fm, x, tg, kern, st0);
    } else {
        init_state_only<<<NBLK, TPB, 0, stream>>>(x, tg, st0);
    }

    unsigned char* cur = st0;
    unsigned char* nxt = st1;
    for (int i = 0; i < ITERS; ++i) {
        if (pre) {
            iter_kernel<true><<<NBLK, TPB, 0, stream>>>(cur, nxt, kern, fm, tg);
        } else {
            iter_kernel<false><<<NBLK, TPB, 0, stream>>>(cur, nxt, kern, fm, tg);
        }
        unsigned char* tmp = cur; cur = nxt; nxt = tmp;
    }

    finalize_kernel<<<NBLK, TPB, 0, stream>>>(cur, out, counts);
    write_valid<<<1, 64, 0, stream>>>(counts, out + NPIX);
}

// Round 2
// 214.091 us; speedup vs baseline: 1.3855x; 1.3855x over previous
//
#include <hip/hip_runtime.h>
#include <math.h>

namespace {

constexpr int Hh = 384;
constexpr int Ww = 384;
constexpr int Bb = 4;
constexpr int HW = Hh * Ww;          // 147456
constexpr int NPIX = Bb * HW;        // 589824
constexpr int ITERS = 20;
constexpr int TPB = 256;
constexpr int NB4 = NPIX / (TPB * 4);        // 576 blocks, 4 px/thread
constexpr int BLKS_PER_B = NB4 / Bb;         // 144

__device__ __forceinline__ float fsub_rn_(float a, float b) {
    return __fadd_rn(a, -b);
}

// 9 pairwise weights for pixel (h,w) of batch-slice fmb = feature_map[b] ([3,HW])
__device__ __forceinline__ void compute_weights(const float* __restrict__ fmb,
                                                int h, int w, int hw,
                                                float* __restrict__ wgt) {
    float c0 = __fadd_rn(fmb[0 * HW + hw], 10.0f);
    float c1 = __fadd_rn(fmb[1 * HW + hw], 10.0f);
    float c2 = __fadd_rn(fmb[2 * HW + hw], 10.0f);
#pragma unroll
    for (int ki = 0; ki < 3; ++ki) {
#pragma unroll
        for (int kj = 0; kj < 3; ++kj) {
            const int k = ki * 3 + kj;
            const int hh = h + ki - 1;
            const int ww2 = w + kj - 1;
            if (hh < 0 || hh >= Hh || ww2 < 0 || ww2 >= Ww) {
                wgt[k] = 0.0f;
            } else {
                const int nhw = hh * Ww + ww2;
                float d0 = fsub_rn_(__fadd_rn(fmb[0 * HW + nhw], 10.0f), c0);
                float d1 = fsub_rn_(__fadd_rn(fmb[1 * HW + nhw], 10.0f), c1);
                float d2 = fsub_rn_(__fadd_rn(fmb[2 * HW + nhw], 10.0f), c2);
                float ss = __fadd_rn(__fadd_rn(__fmul_rn(d0, d0), __fmul_rn(d1, d1)),
                                     __fmul_rn(d2, d2));
                float color = __fdiv_rn(-ss, 0.5f);                 // /(2*0.5^2)
                const float spk = __fdiv_rn(
                    (float)((ki - 1) * (ki - 1) + (kj - 1) * (kj - 1)), 1800.0f);
                wgt[k] = __fmul_rn(3.0f, expf(fsub_rn_(color, spk)));
            }
        }
    }
}

// state byte: bit0 = (channel0 == 0.55f), bit1 = (channel1 == 0.55f)
__global__ __launch_bounds__(TPB) void precomp4_kernel(
        const float* __restrict__ fm, const float* __restrict__ x,
        const float* __restrict__ t, float* __restrict__ kern,
        unsigned char* __restrict__ st) {
    int tid4 = blockIdx.x * TPB + threadIdx.x;
    int p = tid4 * 4;
    int b = p / HW, hw = p - b * HW;
    int h = hw / Ww, w0 = hw - h * Ww;
    const float* fmb = fm + (size_t)b * 3 * HW;

    float wall[9][4];
#pragma unroll
    for (int j = 0; j < 4; ++j) {
        float wgt[9];
        compute_weights(fmb, h, w0 + j, hw + j, wgt);
#pragma unroll
        for (int k = 0; k < 9; ++k) wall[k][j] = wgt[k];
    }
    float4* kb = reinterpret_cast<float4*>(kern + (size_t)b * 9 * HW);
#pragma unroll
    for (int k = 0; k < 9; ++k)
        kb[k * (HW / 4) + (hw >> 2)] =
            make_float4(wall[k][0], wall[k][1], wall[k][2], wall[k][3]);

    float4 xv = reinterpret_cast<const float4*>(x)[tid4];
    float4 tv = reinterpret_cast<const float4*>(t)[tid4];
    uchar4 s4;
    s4.x = (__fmul_rn(xv.x, tv.x) > 0.5f) ? 2 : 1;
    s4.y = (__fmul_rn(xv.y, tv.y) > 0.5f) ? 2 : 1;
    s4.z = (__fmul_rn(xv.z, tv.z) > 0.5f) ? 2 : 1;
    s4.w = (__fmul_rn(xv.w, tv.w) > 0.5f) ? 2 : 1;
    *reinterpret_cast<uchar4*>(st + p) = s4;
}

__global__ __launch_bounds__(TPB) void init_state_only4(
        const float* __restrict__ x, const float* __restrict__ t,
        unsigned char* __restrict__ st) {
    int tid4 = blockIdx.x * TPB + threadIdx.x;
    int p = tid4 * 4;
    float4 xv = reinterpret_cast<const float4*>(x)[tid4];
    float4 tv = reinterpret_cast<const float4*>(t)[tid4];
    uchar4 s4;
    s4.x = (__fmul_rn(xv.x, tv.x) > 0.5f) ? 2 : 1;
    s4.y = (__fmul_rn(xv.y, tv.y) > 0.5f) ? 2 : 1;
    s4.z = (__fmul_rn(xv.z, tv.z) > 0.5f) ? 2 : 1;
    s4.w = (__fmul_rn(xv.w, tv.w) > 0.5f) ? 2 : 1;
    *reinterpret_cast<uchar4*>(st + p) = s4;
}

template <bool PRE, bool FINAL>
__global__ __launch_bounds__(TPB) void iter4_kernel(
        const unsigned char* __restrict__ sin_,
        unsigned char* __restrict__ sout,     // !FINAL
        const float* __restrict__ kern,       // PRE
        const float* __restrict__ fm,         // !PRE
        const float* __restrict__ t,
        float* __restrict__ out,              // FINAL
        int* __restrict__ partial) {          // FINAL
    int tid4 = blockIdx.x * TPB + threadIdx.x;
    int p = tid4 * 4;
    int b = p / HW, hw = p - b * HW;
    int h = hw / Ww, w0 = hw - h * Ww;

    const float Lg45 = (float)(-log((double)0.45f));
    const float Lg55 = (float)(-log((double)0.55f));

    float wall[9][4];
    if (PRE) {
        const float4* kb = reinterpret_cast<const float4*>(kern + (size_t)b * 9 * HW);
#pragma unroll
        for (int k = 0; k < 9; ++k) {
            float4 v = kb[k * (HW / 4) + (hw >> 2)];
            wall[k][0] = v.x; wall[k][1] = v.y; wall[k][2] = v.z; wall[k][3] = v.w;
        }
    } else {
        const float* fmb = fm + (size_t)b * 3 * HW;
#pragma unroll
        for (int j = 0; j < 4; ++j) {
            float wgt[9];
            compute_weights(fmb, h, w0 + j, hw + j, wgt);
#pragma unroll
            for (int k = 0; k < 9; ++k) wall[k][j] = wgt[k];
        }
    }

    const unsigned char* sb = sin_ + (size_t)b * HW;
    float4 tv = reinterpret_cast<const float4*>(t)[tid4];
    float tj[4] = {tv.x, tv.y, tv.z, tv.w};

    unsigned char ns4[4];
    float o4[4];
#pragma unroll
    for (int j = 0; j < 4; ++j) {
        const int w = w0 + j;
        float a0 = 0.0f, a1 = 0.0f;
#pragma unroll
        for (int ki = 0; ki < 3; ++ki) {
            const int hh = h + ki - 1;
            if (hh < 0 || hh >= Hh) continue;
            const unsigned char* row = sb + hh * Ww;
#pragma unroll
            for (int kj = 0; kj < 3; ++kj) {
                const int ww2 = w + kj - 1;
                if (ww2 < 0 || ww2 >= Ww) continue;
                const int k = ki * 3 + kj;
                unsigned char s = row[ww2];
                float u0 = (s & 1) ? Lg55 : Lg45;
                float u1 = (s & 2) ? Lg55 : Lg45;
                a0 = __fadd_rn(a0, __fmul_rn(u0, wall[k][j]));
                a1 = __fadd_rn(a1, __fmul_rn(u1, wall[k][j]));
            }
        }
        float f0 = expf(-a0);
        float f1 = __fmul_rn(expf(-a1), tj[j]);
        f0 = __fadd_rn(f0, 1e-6f);
        f1 = __fadd_rn(f1, 1e-6f);
        float S = __fadd_rn(f0, f1);
        float f1n = __fdiv_rn(f1, S);
        if (FINAL) {
            o4[j] = (f1n > 0.5f) ? 1.0f : 0.0f;
        } else {
            float f0n = __fdiv_rn(f0, S);
            ns4[j] = (unsigned char)((f0n > 0.5f ? 1 : 0) | (f1n > 0.5f ? 2 : 0));
        }
    }

    if (FINAL) {
        reinterpret_cast<float4*>(out)[tid4] = make_float4(o4[0], o4[1], o4[2], o4[3]);
        int cnt = (o4[0] != 0.0f) + (o4[1] != 0.0f) + (o4[2] != 0.0f) + (o4[3] != 0.0f);
        const int lane = threadIdx.x & 63;
        const int wv = threadIdx.x >> 6;
#pragma unroll
        for (int off = 32; off; off >>= 1) cnt += __shfl_down(cnt, off, 64);
        __shared__ int sred[4];
        if (lane == 0) sred[wv] = cnt;
        __syncthreads();
        if (threadIdx.x == 0)
            partial[blockIdx.x] = sred[0] + sred[1] + sred[2] + sred[3];
    } else {
        *reinterpret_cast<uchar4*>(sout + p) =
            make_uchar4(ns4[0], ns4[1], ns4[2], ns4[3]);
    }
}

__global__ void valid_kernel(const int* __restrict__ partial,
                             float* __restrict__ outv) {
    int wv = threadIdx.x >> 6;      // batch 0..3
    int lane = threadIdx.x & 63;
    const int base = wv * BLKS_PER_B;     // 144 partials per batch = 64+64+16
    int s = partial[base + lane] + partial[base + 64 + lane];
    if (lane < 16) s += partial[base + 128 + lane];
#pragma unroll
    for (int off = 32; off; off >>= 1) s += __shfl_down(s, off, 64);
    if (lane == 0) {
        float cf = (float)s;
        const float lo = (float)(147456.0 * 0.05);
        const float hi = (float)(147456.0 * 0.95);
        outv[wv] = (cf >= lo && cf <= hi) ? 1.0f : 0.0f;
    }
}

}  // namespace

extern "C" void kernel_launch(void* const* d_in, const int* in_sizes, int n_in,
                              void* d_out, int out_size, void* d_ws, size_t ws_size,
                              hipStream_t stream) {
    const float* x  = (const float*)d_in[0];
    const float* tg = (const float*)d_in[1];
    const float* fm = (const float*)d_in[2];
    float* out = (float*)d_out;

    const size_t partBytes = (size_t)NB4 * sizeof(int);            // 2304
    const size_t stBytes   = (size_t)NPIX;                         // 589824
    const size_t kernBytes = (size_t)Bb * 9 * HW * sizeof(float);  // ~21.2 MB

    char* ws = (char*)d_ws;
    int* partial = (int*)ws;
    unsigned char* st0 = (unsigned char*)(ws + partBytes);
    unsigned char* st1 = st0 + stBytes;
    float* kern = (float*)(ws + partBytes + 2 * stBytes);          // 16B-aligned
    const bool pre = ws_size >= partBytes + 2 * stBytes + kernBytes;

    if (pre) {
        precomp4_kernel<<<NB4, TPB, 0, stream>>>(fm, x, tg, kern, st0);
    } else {
        init_state_only4<<<NB4, TPB, 0, stream>>>(x, tg, st0);
    }

    unsigned char* cur = st0;
    unsigned char* nxt = st1;
    for (int i = 0; i < ITERS - 1; ++i) {
        if (pre) {
            iter4_kernel<true, false><<<NB4, TPB, 0, stream>>>(
                cur, nxt, kern, fm, tg, nullptr, nullptr);
        } else {
            iter4_kernel<false, false><<<NB4, TPB, 0, stream>>>(
                cur, nxt, kern, fm, tg, nullptr, nullptr);
        }
        unsigned char* tmp = cur; cur = nxt; nxt = tmp;
    }
    // final iteration fused with output + per-block counts
    if (pre) {
        iter4_kernel<true, true><<<NB4, TPB, 0, stream>>>(
            cur, nullptr, kern, fm, tg, out, partial);
    } else {
        iter4_kernel<false, true><<<NB4, TPB, 0, stream>>>(
            cur, nullptr, kern, fm, tg, out, partial);
    }
    valid_kernel<<<1, 256, 0, stream>>>(partial, out + NPIX);
}